// Round 4
// baseline (259.997 us; speedup 1.0000x reference)
//
#include <hip/hip_runtime.h>

#define NB 32
#define NC 128
#define NH 56
#define NW 56
#define HP 58
#define WP 58
#define KK 1152
#define NPOS 3136                         // 56*56
#define XT_BYTES (NB * HP * WP * NC * 2)  // 27,557,888
#define AW_OFF XT_BYTES

typedef __attribute__((ext_vector_type(8))) short s16x8;
typedef __attribute__((ext_vector_type(4))) float f32x4;
typedef unsigned int u32;

__device__ __forceinline__ unsigned short f2bf(float f) {
    union { float f; unsigned int u; } v; v.f = f;
    unsigned int u = v.u + 0x7fffu + ((v.u >> 16) & 1u);
    return (unsigned short)(u >> 16);
}

__device__ __forceinline__ void gld16(const void* g, void* l) {
    __builtin_amdgcn_global_load_lds(
        (const __attribute__((address_space(1))) u32*)g,
        (__attribute__((address_space(3))) u32*)l, 16, 0, 0);
}

// ---- prologue 1: pad + transpose x [B,C,56,56]f32 -> x_t [B,58,58,C]bf16 ----
__global__ void k_xpose(const float* __restrict__ x, unsigned short* __restrict__ xt) {
    __shared__ unsigned short tile[128 * 57];
    int blk = blockIdx.x;
    int b = blk / NH, y = blk % NH;
    int tid = threadIdx.x;
    const float* xb = x + (size_t)b * (NC * NPOS) + y * NW;
#pragma unroll
    for (int p = 0; p < 7; ++p) {
        int idx = p * 256 + tid;            // 1792 float4 = 7168 floats
        int c = idx / 14, i = idx - c * 14;
        float4 v = *(const float4*)(xb + c * NPOS + i * 4);
        unsigned short* tp = &tile[c * 57 + i * 4];
        tp[0] = f2bf(v.x); tp[1] = f2bf(v.y); tp[2] = f2bf(v.z); tp[3] = f2bf(v.w);
    }
    __syncthreads();
    unsigned short* xrow = xt + ((size_t)(b * HP + y + 1) * WP + 1) * NC;
#pragma unroll
    for (int p = 0; p < 4; ++p) {
        int idx = p * 256 + tid;            // 896 = 56 x-pos * 16 chunks
        if (idx < 896) {
            int xp = idx >> 4, cgi = idx & 15;
            s16x8 v8;
#pragma unroll
            for (int j = 0; j < 8; ++j)
                v8[j] = (short)tile[(cgi * 8 + j) * 57 + xp];
            *(s16x8*)(xrow + xp * NC + cgi * 8) = v8;
        }
    }
    if (tid < 128) {
        xt[((size_t)(b * HP + y + 1) * WP + 0) * NC + tid] = 0;
        xt[((size_t)(b * HP + y + 1) * WP + 57) * NC + tid] = 0;
    }
    if (y == 0) {
        unsigned short* r0 = xt + (size_t)(b * HP + 0) * WP * NC;
        for (int i = tid; i < WP * NC; i += 256) r0[i] = 0;
    }
    if (y == 55) {
        unsigned short* r57 = xt + (size_t)(b * HP + 57) * WP * NC;
        for (int i = tid; i < WP * NC; i += 256) r57[i] = 0;
    }
}

// ---- prologue 2: w -> A fragments in exact MFMA lane order ----
// aw[s][mt][lane][j]: byte off = (s*32+mt)*1024 + lane*16 + j*2
// m = mt*16 + (lane&15); k_global = s*32 + (lane>>4)*8 + j
__global__ void k_wconv(const float* __restrict__ w, unsigned short* __restrict__ aw) {
    int idx = blockIdx.x * 256 + threadIdx.x;   // 589824 total
    if (idx >= 512 * KK) return;
    int j = idx & 7, lane = (idx >> 3) & 63, mt = (idx >> 9) & 31, s = idx >> 14;
    int m = mt * 16 + (lane & 15);
    int kg = s * 32 + (lane >> 4) * 8 + j;
    int g = kg >> 7, ic = kg & 127;
    aw[idx] = f2bf(w[(m * 128 + ic) * 9 + g]);
}

// ---- main: barrier-free fused implicit-GEMM conv + softmax combine ----
// 8 waves = 4 ch-groups x 2 n-groups. Wave (mg,ng): ch-tiles {2mg,2mg+1} x 4 ranks
// x NT n-tiles (NT=4 for ng=0, 3 for ng=1). B staged wave-private via
// global_load_lds, double-buffered, synced by s_waitcnt vmcnt(N) only.
template <int NT>
__device__ __forceinline__ void wave_body(
    const unsigned char* __restrict__ xt_b, const unsigned char* __restrict__ gA,
    unsigned char* myL, int bufsz, int tile0, int nbase, int mg, int lane,
    const float* __restrict__ cwr, const float* __restrict__ cwc,
    const float* __restrict__ brow, const float* __restrict__ bcol,
    const float* __restrict__ bch, float* __restrict__ out_b) {
    const int l15 = lane & 15, quad = lane >> 4;

    // per-lane global base for each of NT gld16s (16 rows x 64B each)
    const unsigned char* gB[NT];
#pragma unroll
    for (int i = 0; i < NT; ++i) {
        int row = i * 16 + (lane >> 2);
        int pos = tile0 + nbase + row;
        int yy = pos / 56, xx = pos - yy * 56;
        int lc = (lane & 3) ^ ((lane >> 3) & 3);      // swizzled k-chunk
        gB[i] = xt_b + ((yy + 1) * WP + (xx + 1)) * (NC * 2) + lc * 16;
    }
    // frag read: row=t*16+l15 (stride 64B), phys chunk = quad ^ ((row>>1)&3)
    const int b_base = l15 * 64 + ((quad ^ ((l15 >> 1) & 3)) * 16);

    s16x8 Areg[2][2][4];     // [buf][h][rank]
    f32x4 acc[2][4][NT] = {};  // [h][rank][t]

    auto issue = [&](int st, int buf) {
        int g = st >> 2;
        int dy = (g * 11) >> 5, dx = g - dy * 3;
        int off = ((dy - 1) * WP + (dx - 1)) * (NC * 2) + (st & 3) * 64;
        unsigned char* L = myL + buf * bufsz;
#pragma unroll
        for (int i = 0; i < NT; ++i) gld16(gB[i] + off, L + i * 1024);
#pragma unroll
        for (int h = 0; h < 2; ++h)
#pragma unroll
            for (int r = 0; r < 4; ++r)
                Areg[buf][h][r] = *(const s16x8*)(gA + st * 32768 + h * 1024 + r * 8192);
    };
    auto waitNV = [&]() {   // leave exactly next stage's (NT+8) loads in flight
        if constexpr (NT == 4) asm volatile("s_waitcnt vmcnt(12)" ::: "memory");
        else                   asm volatile("s_waitcnt vmcnt(11)" ::: "memory");
    };
    auto compute = [&](int buf) {
        const unsigned char* L = myL + buf * bufsz;
        s16x8 bf[NT];
#pragma unroll
        for (int t = 0; t < NT; ++t) bf[t] = *(const s16x8*)(L + t * 1024 + b_base);
#pragma unroll
        for (int h = 0; h < 2; ++h)
#pragma unroll
            for (int r = 0; r < 4; ++r)
#pragma unroll
                for (int t = 0; t < NT; ++t)
                    acc[h][r][t] = __builtin_amdgcn_mfma_f32_16x16x32_bf16(
                        Areg[buf][h][r], bf[t], acc[h][r][t], 0, 0, 0);
    };

    issue(0, 0);
    for (int s = 0; s < 34; s += 2) {
        issue(s + 1, 1); waitNV(); compute(0);
        issue(s + 2, 0); waitNV(); compute(1);
    }
    issue(35, 1); waitNV(); compute(0);
    asm volatile("s_waitcnt vmcnt(0)" ::: "memory");
    compute(1);

    // epilogue: softmax over rank + combine + biases
#pragma unroll
    for (int t = 0; t < NT; ++t) {
        int pos = tile0 + nbase + t * 16 + l15;
        int yy = pos / 56, xx = pos - yy * 56;
        float v0 = cwr[yy]       + cwc[xx];
        float v1 = cwr[56 + yy]  + cwc[56 + xx];
        float v2 = cwr[112 + yy] + cwc[112 + xx];
        float v3 = cwr[168 + yy] + cwc[168 + xx];
        float mx = fmaxf(fmaxf(v0, v1), fmaxf(v2, v3));
        float e0 = __expf(v0 - mx), e1 = __expf(v1 - mx);
        float e2 = __expf(v2 - mx), e3 = __expf(v3 - mx);
        float inv = 1.0f / (e0 + e1 + e2 + e3);
        float c0 = e0 * inv, c1 = e1 * inv, c2 = e2 * inv, c3 = e3 * inv;
        float rb = brow[yy] + bcol[xx];
#pragma unroll
        for (int h = 0; h < 2; ++h)
#pragma unroll
            for (int r = 0; r < 4; ++r) {
                int ch = (2 * mg + h) * 16 + quad * 4 + r;
                float v = acc[h][0][t][r] * c0 + acc[h][1][t][r] * c1
                        + acc[h][2][t][r] * c2 + acc[h][3][t][r] * c3;
                out_b[(size_t)ch * NPOS + pos] = v + bch[ch] + rb;
            }
    }
}

__global__ void __launch_bounds__(512, 2) k_main(
    const unsigned short* __restrict__ xt, const unsigned short* __restrict__ aw,
    const float* __restrict__ cwr, const float* __restrict__ cwc,
    const float* __restrict__ brow, const float* __restrict__ bcol,
    const float* __restrict__ bch, float* __restrict__ out) {
    __shared__ __align__(16) unsigned char ldsB[57344];  // 4 x (2x4KB + 2x3KB)

    const int tid = threadIdx.x;
    const int lane = tid & 63;
    const int wv = tid >> 6;
    const int mg = wv >> 1, ng = wv & 1;
    const int blk = blockIdx.x;
    const int b = blk / 28;
    const int tile0 = (blk - b * 28) * 112;

    const unsigned char* xt_b = (const unsigned char*)xt + (size_t)b * (HP * WP * NC * 2);
    const unsigned char* gA = (const unsigned char*)aw + (2 * mg) * 1024 + lane * 16;
    unsigned char* myL = ldsB + mg * 14336 + ng * 8192;
    float* out_b = out + (size_t)b * NC * NPOS;

    if (ng == 0)
        wave_body<4>(xt_b, gA, myL, 4096, tile0, 0, mg, lane,
                     cwr, cwc, brow, bcol, bch, out_b);
    else
        wave_body<3>(xt_b, gA, myL, 3072, tile0, 64, mg, lane,
                     cwr, cwc, brow, bcol, bch, out_b);
}

extern "C" void kernel_launch(void* const* d_in, const int* in_sizes, int n_in,
                              void* d_out, int out_size, void* d_ws, size_t ws_size,
                              hipStream_t stream) {
    const float* x    = (const float*)d_in[0];
    const float* w    = (const float*)d_in[1];
    const float* cwr  = (const float*)d_in[2];
    const float* cwc  = (const float*)d_in[3];
    const float* brow = (const float*)d_in[4];
    const float* bcol = (const float*)d_in[5];
    const float* bch  = (const float*)d_in[6];
    float* out = (float*)d_out;

    unsigned char* ws = (unsigned char*)d_ws;
    unsigned short* xt = (unsigned short*)ws;
    unsigned short* aw = (unsigned short*)(ws + AW_OFF);

    k_xpose<<<NB * NH, 256, 0, stream>>>(x, xt);           // 1792 blocks
    k_wconv<<<(512 * KK) / 256, 256, 0, stream>>>(w, aw);  // 2304 blocks
    k_main<<<NB * 28, 512, 0, stream>>>(xt, aw, cwr, cwc, brow, bcol, bch, out);
}

// Round 5
// 234.124 us; speedup vs baseline: 1.1105x; 1.1105x over previous
//
#include <hip/hip_runtime.h>

#define NB 32
#define NC 128
#define NH 56
#define NW 56
#define HP 58
#define WP 58
#define KK 1152
#define NPOS 3136                         // 56*56
#define XT_BYTES (NB * HP * WP * NC * 2)  // 27,557,888
#define AW_OFF XT_BYTES

typedef __attribute__((ext_vector_type(8))) short s16x8;
typedef __attribute__((ext_vector_type(4))) float f32x4;
typedef unsigned int u32;

__device__ __forceinline__ unsigned short f2bf(float f) {
    union { float f; unsigned int u; } v; v.f = f;
    unsigned int u = v.u + 0x7fffu + ((v.u >> 16) & 1u);
    return (unsigned short)(u >> 16);
}

__device__ __forceinline__ void gld16(const void* g, void* l) {
    __builtin_amdgcn_global_load_lds(
        (const __attribute__((address_space(1))) u32*)g,
        (__attribute__((address_space(3))) u32*)l, 16, 0, 0);
}

// ---- fused prologue: blocks [0,1792) transpose x; [1792,4096) permute w ----
// xpose: [B,C,56,56]f32 -> x_t [B,58,58,C]bf16 (padded, halo zeroed)
// wconv: w -> A fragments in exact MFMA lane order:
//   aw[s32][mt][lane][j]; m=mt*16+(lane&15); k=s32*32+(lane>>4)*8+j; k=(tap)*128+ic
__global__ void k_pro(const float* __restrict__ x, const float* __restrict__ w,
                      unsigned short* __restrict__ xt, unsigned short* __restrict__ aw) {
    int blk = blockIdx.x;
    int tid = threadIdx.x;
    if (blk >= 1792) {
        int idx = (blk - 1792) * 256 + tid;   // 589824 total
        if (idx < 512 * KK) {
            int j = idx & 7, lane = (idx >> 3) & 63, mt = (idx >> 9) & 31, s = idx >> 14;
            int m = mt * 16 + (lane & 15);
            int kg = s * 32 + (lane >> 4) * 8 + j;
            int g = kg >> 7, ic = kg & 127;
            aw[idx] = f2bf(w[(m * 128 + ic) * 9 + g]);
        }
        return;
    }
    __shared__ unsigned short tile[128 * 57];
    int b = blk / NH, y = blk % NH;
    const float* xb = x + (size_t)b * (NC * NPOS) + y * NW;
#pragma unroll
    for (int p = 0; p < 7; ++p) {
        int idx = p * 256 + tid;            // 1792 float4 = 7168 floats
        int c = idx / 14, i = idx - c * 14;
        float4 v = *(const float4*)(xb + c * NPOS + i * 4);
        unsigned short* tp = &tile[c * 57 + i * 4];
        tp[0] = f2bf(v.x); tp[1] = f2bf(v.y); tp[2] = f2bf(v.z); tp[3] = f2bf(v.w);
    }
    __syncthreads();
    unsigned short* xrow = xt + ((size_t)(b * HP + y + 1) * WP + 1) * NC;
#pragma unroll
    for (int p = 0; p < 4; ++p) {
        int idx = p * 256 + tid;            // 896 = 56 x-pos * 16 chunks
        if (idx < 896) {
            int xp = idx >> 4, cgi = idx & 15;
            s16x8 v8;
#pragma unroll
            for (int j = 0; j < 8; ++j)
                v8[j] = (short)tile[(cgi * 8 + j) * 57 + xp];
            *(s16x8*)(xrow + xp * NC + cgi * 8) = v8;
        }
    }
    if (tid < 128) {
        xt[((size_t)(b * HP + y + 1) * WP + 0) * NC + tid] = 0;
        xt[((size_t)(b * HP + y + 1) * WP + 57) * NC + tid] = 0;
    }
    if (y == 0) {
        unsigned short* r0 = xt + (size_t)(b * HP + 0) * WP * NC;
        for (int i = tid; i < WP * NC; i += 256) r0[i] = 0;
    }
    if (y == 55) {
        unsigned short* r57 = xt + (size_t)(b * HP + 57) * WP * NC;
        for (int i = tid; i < WP * NC; i += 256) r57[i] = 0;
    }
}

// ---- main: fused implicit-GEMM conv + softmax rank combine + biases ----
// 8 waves, M=512 (4 ranks x 128 ch), N=112 (2 image rows), K=1152.
// 9 barrier-stages of K=128 = exactly one 3x3 filter tap each (B-row = 256B
// contiguous). A: global->VGPR, ping-ponged per K32 sub-step (compiler vmcnt).
// B: shared LDS, double-buffered (2 x 28KB), staged by waves 0..6 via gld16.
// Swizzle: phys 16B chunk = global chunk ^ (row & 15)  -> frag reads <=2-way.
__global__ void __launch_bounds__(512, 2) k_main(
    const unsigned short* __restrict__ xt, const unsigned short* __restrict__ aw,
    const float* __restrict__ cwr, const float* __restrict__ cwc,
    const float* __restrict__ brow, const float* __restrict__ bcol,
    const float* __restrict__ bch, float* __restrict__ out) {
    __shared__ __align__(16) unsigned char ldsB[2][28672];   // 112 rows x 256B

    const int tid = threadIdx.x;
    const int lane = tid & 63;
    const int wv = tid >> 6;
    const int l15 = lane & 15, quad = lane >> 4;
    const int blk = blockIdx.x;
    const int b = blk / 28;
    const int tile0 = (blk - b * 28) * 112;

    const unsigned char* xt_b = (const unsigned char*)xt + (size_t)b * (HP * WP * NC * 2);
    const unsigned char* gA = (const unsigned char*)aw + wv * 1024 + lane * 16;

    // B staging: wave wv (0..6) stages rows wv*16..+15; gld16 #h covers 4 rows
    // (h*4 + lane>>4), phys chunk lane&15, global chunk (lane&15)^(row&15).
    const unsigned char* gB[4];
    if (wv < 7) {
#pragma unroll
        for (int h = 0; h < 4; ++h) {
            int rl = h * 4 + (lane >> 4);
            int row = wv * 16 + rl;
            int pos = tile0 + row;
            int yy = pos / 56, xx = pos - yy * 56;
            int c = (lane & 15) ^ rl;
            gB[h] = xt_b + ((yy + 1) * WP + (xx + 1)) * (NC * 2) + c * 16;
        }
    }

    s16x8 Areg[2][4];          // [pingpong][rank]
    f32x4 acc[4][7] = {};      // [rank][ntile]

    auto aload = [&](int s32, int pp) {
#pragma unroll
        for (int r = 0; r < 4; ++r)
            Areg[pp][r] = *(const s16x8*)(gA + s32 * 32768 + r * 8192);
    };
    auto bissue = [&](int st, int buf) {
        if (wv < 7) {
            int dy = (st * 11) >> 5, dx = st - dy * 3;
            int off = ((dy - 1) * WP + (dx - 1)) * (NC * 2);
            unsigned char* L = &ldsB[buf][wv * 4096];
#pragma unroll
            for (int h = 0; h < 4; ++h) gld16(gB[h] + off, L + h * 1024);
        }
    };

    aload(0, 0);
    bissue(0, 0);
    __syncthreads();

    for (int st = 0; st < 9; ++st) {
        const int cur = st & 1;
        if (st < 8) bissue(st + 1, cur ^ 1);
        const unsigned char* L = &ldsB[cur][0];
#pragma unroll
        for (int kk = 0; kk < 4; ++kk) {
            if (kk < 3) aload(st * 4 + kk + 1, (kk + 1) & 1);
            else if (st < 8) aload((st + 1) * 4, 0);
            s16x8 bf[7];
#pragma unroll
            for (int t = 0; t < 7; ++t)
                bf[t] = *(const s16x8*)(L + (t * 16 + l15) * 256
                                          + (((kk * 4 + quad) ^ l15) << 4));
#pragma unroll
            for (int r = 0; r < 4; ++r)
#pragma unroll
                for (int t = 0; t < 7; ++t)
                    acc[r][t] = __builtin_amdgcn_mfma_f32_16x16x32_bf16(
                        Areg[kk & 1][r], bf[t], acc[r][t], 0, 0, 0);
        }
        __syncthreads();
    }

    // epilogue: inline softmax over rank + combine + biases, fp32 store
#pragma unroll
    for (int t = 0; t < 7; ++t) {
        int pos = tile0 + t * 16 + l15;
        int yy = pos / 56, xx = pos - yy * 56;
        float v0 = cwr[yy]       + cwc[xx];
        float v1 = cwr[56 + yy]  + cwc[56 + xx];
        float v2 = cwr[112 + yy] + cwc[112 + xx];
        float v3 = cwr[168 + yy] + cwc[168 + xx];
        float mx = fmaxf(fmaxf(v0, v1), fmaxf(v2, v3));
        float e0 = __expf(v0 - mx), e1 = __expf(v1 - mx);
        float e2 = __expf(v2 - mx), e3 = __expf(v3 - mx);
        float inv = 1.0f / (e0 + e1 + e2 + e3);
        float c0 = e0 * inv, c1 = e1 * inv, c2 = e2 * inv, c3 = e3 * inv;
        float rb = brow[yy] + bcol[xx];
#pragma unroll
        for (int r = 0; r < 4; ++r) {
            int ch = wv * 16 + quad * 4 + r;
            float v = acc[0][t][r] * c0 + acc[1][t][r] * c1
                    + acc[2][t][r] * c2 + acc[3][t][r] * c3;
            out[((size_t)b * NC + ch) * NPOS + pos] = v + bch[ch] + rb;
        }
    }
}

extern "C" void kernel_launch(void* const* d_in, const int* in_sizes, int n_in,
                              void* d_out, int out_size, void* d_ws, size_t ws_size,
                              hipStream_t stream) {
    const float* x    = (const float*)d_in[0];
    const float* w    = (const float*)d_in[1];
    const float* cwr  = (const float*)d_in[2];
    const float* cwc  = (const float*)d_in[3];
    const float* brow = (const float*)d_in[4];
    const float* bcol = (const float*)d_in[5];
    const float* bch  = (const float*)d_in[6];
    float* out = (float*)d_out;

    unsigned char* ws = (unsigned char*)d_ws;
    unsigned short* xt = (unsigned short*)ws;
    unsigned short* aw = (unsigned short*)(ws + AW_OFF);

    k_pro<<<4096, 256, 0, stream>>>(x, w, xt, aw);   // xpose + wconv fused
    k_main<<<NB * 28, 512, 0, stream>>>(xt, aw, cwr, cwc, brow, bcol, bch, out);
}